// Round 7
// baseline (1286.828 us; speedup 1.0000x reference)
//
#include <hip/hip_runtime.h>
#include <math.h>

// Problem constants (fixed shapes from setup_inputs)
#define Dn   12
#define Hn   448
#define Wn   224
#define HWn  (Hn*Wn)        // 100352
#define DHWn (Dn*HWn)       // 1204224
#define Cn   10

// Twiddle table (float2 in global):
#define TW_W32   0     // 16: W32^j
#define TW_W7    30    // 7:  W7^j
#define TW_B224  69    // 32: W224^j (j<32)
#define TW_B448L 101   // 64: W448^a (a<64)  -- colfft lane twiddle
#define TW_W64   165   // 32: W64^j (j<32)
#define TW_N2    197

// ---------- complex helpers ----------
__device__ __forceinline__ float2 cmul(float2 a, float2 b) {
    return make_float2(fmaf(a.x, b.x, -a.y * b.y), fmaf(a.x, b.y, a.y * b.x));
}
__device__ __forceinline__ float2 cfma(float2 a, float2 b, float2 acc) {
    acc.x = fmaf(a.x, b.x, fmaf(-a.y, b.y, acc.x));
    acc.y = fmaf(a.x, b.y, fmaf(a.y, b.x, acc.y));
    return acc;
}
__device__ __forceinline__ float2 cadd(float2 a, float2 b) { return make_float2(a.x + b.x, a.y + b.y); }
__host__ __device__ constexpr int brev5(int i) {
    return ((i & 1) << 4) | ((i & 2) << 2) | (i & 4) | ((i & 8) >> 2) | ((i & 16) >> 4);
}

__device__ __forceinline__ float2 shflx2(float2 v, int m) {
    return make_float2(__shfl_xor(v.x, m, 64), __shfl_xor(v.y, m, 64));
}

__device__ __forceinline__ double waveReduce(double v) {
#pragma unroll
    for (int o = 32; o > 0; o >>= 1) v += __shfl_down(v, o, 64);
    return v;
}

// log-depth twiddle powers tp[j] = base^j (depth <= 4)
template<int NP>
__device__ __forceinline__ void twpow(float2 (&tp)[NP], float2 base) {
    tp[0] = make_float2(1.f, 0.f);
    tp[1] = base;
#pragma unroll
    for (int j = 2; j < NP; ++j) tp[j] = cmul(tp[j >> 1], tp[j - (j >> 1)]);
}

// ---------- init kernels ----------
__global__ void k_init_misc(float2* __restrict__ tws, double* __restrict__ S) {
    int t = threadIdx.x;  // 256 threads
    const double PI2 = 6.283185307179586476925287;
    if (t < 16)             { double s, c; sincos(-(PI2 * t) / 32.0,  &s, &c); tws[TW_W32 + t]  = make_float2((float)c, (float)s); }
    if (t >= 30 && t < 37)  { int j = t - 30; double s, c; sincos(-(PI2 * j) / 7.0,  &s, &c); tws[TW_W7 + j]  = make_float2((float)c, (float)s); }
    if (t >= 69 && t < 101) { int j = t - 69; double s, c; sincos(-(PI2 * j) / 224.0, &s, &c); tws[TW_B224 + j] = make_float2((float)c, (float)s); }
    if (t >= 101 && t < 165){ int j = t - 101; double s, c; sincos(-(PI2 * j) / 448.0, &s, &c); tws[TW_B448L + j] = make_float2((float)c, (float)s); }
    if (t >= 165 && t < 197){ int j = t - 165; double s, c; sincos(-(PI2 * j) / 64.0,  &s, &c); tws[TW_W64 + j]  = make_float2((float)c, (float)s); }
    if (t >= 197 && t < 229) S[t - 197] = 0.0;
}

__global__ void k_build_p(const float* __restrict__ z, const float* __restrict__ zf,
                          const float* __restrict__ miu,
                          float2* __restrict__ p, float2* __restrict__ r, float2* __restrict__ b,
                          double* __restrict__ S) {
    float mu = fabsf(miu[0]);
    double acc = 0.0;
    for (int e = blockIdx.x * blockDim.x + threadIdx.x; e < DHWn; e += gridDim.x * blockDim.x) {
        int d = e / HWn, rem = e - d * HWn;
        int h = rem / Wn, w = rem - h * Wn;
        int hs = h + Hn / 2; if (hs >= Hn) hs -= Hn;
        int ws = w + Wn / 2; if (ws >= Wn) ws -= Wn;
        int src = d * HWn + hs * Wn + ws;
        float pr = fmaf(mu, z[src], zf[src]);
        float pi = fmaf(mu, z[DHWn + src], zf[DHWn + src]);
        float2 v = make_float2(pr, pi);
        p[e] = v; r[e] = v; b[e] = make_float2(0.f, 0.f);
        acc += (double)pr * pr + (double)pi * pi;
    }
    acc = waveReduce(acc);
    if ((threadIdx.x & 63) == 0) atomicAdd(&S[0], acc);
}

__global__ void k_build_coil(const float* __restrict__ cr, const float* __restrict__ ci,
                             float2* __restrict__ coil) {
    for (int e = blockIdx.x * blockDim.x + threadIdx.x; e < Cn * HWn; e += gridDim.x * blockDim.x) {
        int c = e / HWn, rem = e - c * HWn;
        int h = rem / Wn, w = rem - h * Wn;
        int hs = h + Hn / 2; if (hs >= Hn) hs -= Hn;
        int ws = w + Wn / 2; if (ws >= Wn) ws -= Wn;
        int src = c * HWn + hs * Wn + ws;
        coil[e] = make_float2(cr[src], ci[src]);
    }
}

// permuted + shifted + scaled mask: maskP[L*448 + h], line L holds true
// frequency column w(L) = 7*brev5(L&31) + (L>>5)
__global__ void k_build_mask(const int* __restrict__ mask, float* __restrict__ maskP) {
    for (int e = blockIdx.x * blockDim.x + threadIdx.x; e < HWn; e += gridDim.x * blockDim.x) {
        int L = e / Hn, h = e - L * Hn;
        int w = 7 * brev5(L & 31) + (L >> 5);
        int hs = h + Hn / 2; if (hs >= Hn) hs -= Hn;
        int ws = w + Wn / 2; if (ws >= Wn) ws -= Wn;
        maskP[e] = (float)mask[hs * Wn + ws] * (1.0f / (float)HWn);
    }
}

// ---------- forward row FFT (224 = 7*32 lane-FFT), coil-mul, write Y1T lines ----------
#define BPITCH 226
__global__ __launch_bounds__(256) void k_rowfft0(const float2* __restrict__ P,
                                                 const float2* __restrict__ coil,
                                                 float2* __restrict__ Y1T,
                                                 const float2* __restrict__ twg,
                                                 int chunkStart) {
    __shared__ float2 buf[8][BPITCH];
    int tid = threadIdx.x;
    int lane = tid & 63, wv = tid >> 6, hi = lane >> 5, l32 = lane & 31;
    int h0 = blockIdx.x * 8, d = blockIdx.y, cz = blockIdx.z;
    int row = h0 + 2 * wv + hi;
    const float2* w32g = twg + TW_W32;
    const float2* w7g  = twg + TW_W7;
    const float2* b224 = twg + TW_B224;

    const float2* prow = P + (size_t)d * HWn + (size_t)row * Wn;
    const float2* crow = coil + (size_t)(chunkStart + cz) * HWn + (size_t)row * Wn;

    float2 xb[7];
#pragma unroll
    for (int b = 0; b < 7; ++b) xb[b] = cmul(prow[32 * b + l32], crow[32 * b + l32]);

    // DFT7
    float2 y[7];
#pragma unroll
    for (int d7 = 0; d7 < 7; ++d7) {
        float2 s = xb[0];
#pragma unroll
        for (int b = 1; b < 7; ++b) s = cfma(xb[b], w7g[(b * d7) % 7], s);
        y[d7] = s;
    }
    // twiddle W224^{l32*d7}
    float2 tp[7]; twpow(tp, b224[l32]);
#pragma unroll
    for (int d7 = 1; d7 < 7; ++d7) y[d7] = cmul(y[d7], tp[d7]);

    // FFT32 across each half-wave, DIF (postmultiply form)
#pragma unroll
    for (int s = 0; s < 5; ++s) {
        int dist = 16 >> s;
        float2 w = w32g[(l32 & (dist - 1)) << s];
        bool h2 = (l32 & dist) != 0;
        float sgn = h2 ? -1.f : 1.f;
        float2 wsel = h2 ? w : make_float2(1.f, 0.f);
#pragma unroll
        for (int d7 = 0; d7 < 7; ++d7) {
            float2 t = shflx2(y[d7], dist);
            float2 v = make_float2(fmaf(sgn, y[d7].x, t.x), fmaf(sgn, y[d7].y, t.y));
            y[d7] = cmul(v, wsel);
        }
    }

    // deposit to LDS: line L = d7*32 + l32
#pragma unroll
    for (int d7 = 0; d7 < 7; ++d7) buf[2 * wv + hi][d7 * 32 + l32] = y[d7];
    __syncthreads();

    float2* img = Y1T + ((size_t)cz * Dn + d) * (size_t)HWn;
#pragma unroll
    for (int k = 0; k < 7; ++k) {
        int i = tid + k * 256;
        int hh = i & 7, L = i >> 3;
        img[(size_t)L * Hn + h0 + hh] = buf[hh][L];
    }
}

// ---------- column FFT448 + mask + IFFT448, pure register lane-FFT ----------
__global__ __launch_bounds__(256) void k_colfft(float2* __restrict__ Y1T,
                                                const float* __restrict__ maskP,
                                                const float2* __restrict__ twg) {
    __shared__ float2 tws[TW_N2];
    int tid = threadIdx.x;
    int lane = tid & 63, wv = tid >> 6;
    for (int i = tid; i < TW_N2; i += 256) tws[i] = twg[i];
    __syncthreads();

    const float2* w7t  = tws + TW_W7;
    const float2* w64t = tws + TW_W64;
    const float2* b448l = tws + TW_B448L;

    int L = blockIdx.x * 4 + wv;
    int d = blockIdx.y, cz = blockIdx.z;
    float2* line = Y1T + ((size_t)cz * Dn + d) * (size_t)HWn + (size_t)L * Hn;

    float2 xb[7];
#pragma unroll
    for (int b = 0; b < 7; ++b) xb[b] = line[64 * b + lane];

    // forward DFT7
    float2 y[7];
#pragma unroll
    for (int d7 = 0; d7 < 7; ++d7) {
        float2 s = xb[0];
#pragma unroll
        for (int b = 1; b < 7; ++b) s = cfma(xb[b], w7t[(b * d7) % 7], s);
        y[d7] = s;
    }
    float2 tp[7]; twpow(tp, b448l[lane]);
#pragma unroll
    for (int d7 = 1; d7 < 7; ++d7) y[d7] = cmul(y[d7], tp[d7]);

    // FFT64 across lanes, DIF (postmultiply form)
#pragma unroll
    for (int s = 0; s < 6; ++s) {
        int dist = 32 >> s;
        float2 w = w64t[(lane & (dist - 1)) << s];
        bool hi = (lane & dist) != 0;
        float sgn = hi ? -1.f : 1.f;
        float2 wsel = hi ? w : make_float2(1.f, 0.f);
#pragma unroll
        for (int d7 = 0; d7 < 7; ++d7) {
            float2 t = shflx2(y[d7], dist);
            float2 v = make_float2(fmaf(sgn, y[d7].x, t.x), fmaf(sgn, y[d7].y, t.y));
            y[d7] = cmul(v, wsel);
        }
    }

    // mask: lane holds H-freq index 7*brev6(lane)+d7
    int rb = (brev5(lane & 31) << 1) | (lane >> 5);
    const float* mrow = maskP + (size_t)L * Hn + 7 * rb;
#pragma unroll
    for (int d7 = 0; d7 < 7; ++d7) {
        float m = mrow[d7];
        y[d7].x *= m; y[d7].y *= m;
    }

    // inverse FFT64, DIT (premultiply form)
#pragma unroll
    for (int s = 0; s < 6; ++s) {
        int dist = 1 << s;
        float2 w = w64t[(lane & (dist - 1)) << (5 - s)];
        w.y = -w.y;
        bool hi = (lane & dist) != 0;
        float sgn = hi ? -1.f : 1.f;
        float2 wpre = hi ? w : make_float2(1.f, 0.f);
#pragma unroll
        for (int d7 = 0; d7 < 7; ++d7) {
            float2 z = cmul(y[d7], wpre);
            float2 t = shflx2(z, dist);
            y[d7] = make_float2(fmaf(sgn, z.x, t.x), fmaf(sgn, z.y, t.y));
        }
    }
#pragma unroll
    for (int d7 = 1; d7 < 7; ++d7) {
        float2 c = make_float2(tp[d7].x, -tp[d7].y);
        y[d7] = cmul(y[d7], c);
    }
#pragma unroll
    for (int b = 0; b < 7; ++b) {
        float2 s = y[0];
#pragma unroll
        for (int d7 = 1; d7 < 7; ++d7) {
            float2 wq = w7t[(b * d7) % 7]; wq.y = -wq.y;
            s = cfma(y[d7], wq, s);
        }
        xb[b] = s;
    }
#pragma unroll
    for (int b = 0; b < 7; ++b) line[64 * b + lane] = xb[b];
}

// ---------- fused inverse row FFT + conj-coil + coil-sum + q/dot epilogue ----------
// Register-prefetch pipeline: strip cz+1 and coil row cz load into VGPRs while
// computing cz — vmcnt drain only at the next ds_write, not before compute.
__global__ __launch_bounds__(256) void k_irow_combine(const float2* __restrict__ Y1T,
                                                      const float2* __restrict__ coil,
                                                      const float2* __restrict__ P,
                                                      float2* __restrict__ Q,
                                                      const float* __restrict__ miu,
                                                      double* __restrict__ S,
                                                      const float2* __restrict__ twg,
                                                      int cc, int chunkStart,
                                                      int first, int last, int it) {
    __shared__ float2 buf[8][BPITCH];
    int tid = threadIdx.x;
    int lane = tid & 63, wv = tid >> 6, hi = lane >> 5, l32 = lane & 31;
    int h0 = blockIdx.x * 8, d = blockIdx.y;
    int row = h0 + 2 * wv + hi;
    const float2* w32g = twg + TW_W32;
    const float2* w7g  = twg + TW_W7;
    const float2* b224 = twg + TW_B224;

    float2 tp[7]; twpow(tp, b224[l32]);

    float2 acc[7];
#pragma unroll
    for (int b = 0; b < 7; ++b) acc[b] = make_float2(0.f, 0.f);

    // prefetch strip for cz=0
    float2 pre[7];
    {
        const float2* img0 = Y1T + (size_t)d * HWn;
#pragma unroll
        for (int k = 0; k < 7; ++k) {
            int i = tid + k * 256;
            int hh = i & 7, L = i >> 3;
            pre[k] = img0[(size_t)L * Hn + h0 + hh];
        }
    }

    for (int cz = 0; cz < cc; ++cz) {
        __syncthreads();   // previous compute finished reading buf
#pragma unroll
        for (int k = 0; k < 7; ++k) {
            int i = tid + k * 256;
            int hh = i & 7, L = i >> 3;
            buf[hh][L] = pre[k];
        }
        __syncthreads();

        // prefetch next strip (overlaps compute below)
        if (cz + 1 < cc) {
            const float2* imgn = Y1T + ((size_t)(cz + 1) * Dn + d) * (size_t)HWn;
#pragma unroll
            for (int k = 0; k < 7; ++k) {
                int i = tid + k * 256;
                int hh = i & 7, L = i >> 3;
                pre[k] = imgn[(size_t)L * Hn + h0 + hh];
            }
        }
        // prefetch this coil's row (used at end of compute)
        const float2* crow = coil + (size_t)(chunkStart + cz) * HWn + (size_t)row * Wn;
        float2 cpre[7];
#pragma unroll
        for (int b = 0; b < 7; ++b) cpre[b] = crow[32 * b + l32];

        // lane l32 reads line L = d7*32 + l32 (DIT-ready bit-rev order)
        float2 y[7];
#pragma unroll
        for (int d7 = 0; d7 < 7; ++d7) y[d7] = buf[2 * wv + hi][d7 * 32 + l32];

        // inverse FFT32 across half-wave, DIT (premultiply form)
#pragma unroll
        for (int s = 0; s < 5; ++s) {
            int dist = 1 << s;
            float2 w = w32g[(l32 & (dist - 1)) << (4 - s)];
            w.y = -w.y;
            bool h2 = (l32 & dist) != 0;
            float sgn = h2 ? -1.f : 1.f;
            float2 wpre = h2 ? w : make_float2(1.f, 0.f);
#pragma unroll
            for (int d7 = 0; d7 < 7; ++d7) {
                float2 z = cmul(y[d7], wpre);
                float2 t = shflx2(z, dist);
                y[d7] = make_float2(fmaf(sgn, z.x, t.x), fmaf(sgn, z.y, t.y));
            }
        }
        // conj twiddle W224^{-l32*d7}
#pragma unroll
        for (int d7 = 1; d7 < 7; ++d7) {
            float2 c = make_float2(tp[d7].x, -tp[d7].y);
            y[d7] = cmul(y[d7], c);
        }
        // inverse DFT7 + conj-coil accumulate
#pragma unroll
        for (int b = 0; b < 7; ++b) {
            float2 s = y[0];
#pragma unroll
            for (int d7 = 1; d7 < 7; ++d7) {
                float2 wq = w7g[(b * d7) % 7]; wq.y = -wq.y;
                s = cfma(y[d7], wq, s);
            }
            float2 c = cpre[b];
            acc[b].x += fmaf(s.x, c.x, s.y * c.y);
            acc[b].y += fmaf(s.y, c.x, -s.x * c.y);
        }
    }

    // epilogue: q = mu*p + acc (or q += acc), dots on last chunk
    float mu = fabsf(miu[0]);
    const float2* prow = P + (size_t)d * HWn + (size_t)row * Wn;
    float2* qrow = Q + (size_t)d * HWn + (size_t)row * Wn;
    double ar = 0.0, ai = 0.0;
#pragma unroll
    for (int b = 0; b < 7; ++b) {
        float2 pv = prow[32 * b + l32];
        float2 s0;
        if (first) s0 = make_float2(fmaf(mu, pv.x, acc[b].x), fmaf(mu, pv.y, acc[b].y));
        else { float2 qv = qrow[32 * b + l32]; s0 = cadd(qv, acc[b]); }
        qrow[32 * b + l32] = s0;
        if (last) {
            ar += (double)(s0.x * pv.x + s0.y * pv.y);
            ai += (double)(s0.y * pv.x - s0.x * pv.y);
        }
    }
    if (last) {
        ar = waveReduce(ar);
        ai = waveReduce(ai);
        if ((threadIdx.x & 63) == 0) {
            atomicAdd(&S[8 + it], ar);
            atomicAdd(&S[16 + it], ai);
        }
    }
}

// ---------- CG scalar updates (float4 = 2 complex per lane) ----------
__global__ void k_update_br(const double* __restrict__ Sin, double* __restrict__ S, int it,
                            const float4* __restrict__ p, const float4* __restrict__ q,
                            float4* __restrict__ b, float4* __restrict__ r) {
    double rr = Sin[it], qr = Sin[8 + it], qi = Sin[16 + it];
    double den = qr * qr + qi * qi;
    float arf = (float)(rr * qr / den);
    float aif = (float)(-rr * qi / den);
    double acc = 0.0;
    const int N2 = DHWn / 2;
    for (int e = blockIdx.x * blockDim.x + threadIdx.x; e < N2; e += gridDim.x * blockDim.x) {
        float4 pv = p[e], qv = q[e], bv = b[e], rv = r[e];
        bv.x += arf * pv.x - aif * pv.y;  bv.y += arf * pv.y + aif * pv.x;
        bv.z += arf * pv.z - aif * pv.w;  bv.w += arf * pv.w + aif * pv.z;
        b[e] = bv;
        rv.x -= arf * qv.x - aif * qv.y;  rv.y -= arf * qv.y + aif * qv.x;
        rv.z -= arf * qv.z - aif * qv.w;  rv.w -= arf * qv.w + aif * qv.z;
        r[e] = rv;
        acc += (double)rv.x * rv.x + (double)rv.y * rv.y
             + (double)rv.z * rv.z + (double)rv.w * rv.w;
    }
    acc = waveReduce(acc);
    if ((threadIdx.x & 63) == 0) atomicAdd(&S[it + 1], acc);
}

__global__ void k_update_p(const double* __restrict__ S, int it,
                           const float4* __restrict__ r, float4* __restrict__ p) {
    float beta = (float)(S[it + 1] / S[it]);
    const int N2 = DHWn / 2;
    for (int e = blockIdx.x * blockDim.x + threadIdx.x; e < N2; e += gridDim.x * blockDim.x) {
        float4 rv = r[e], pv = p[e];
        p[e] = make_float4(fmaf(beta, pv.x, rv.x), fmaf(beta, pv.y, rv.y),
                           fmaf(beta, pv.z, rv.z), fmaf(beta, pv.w, rv.w));
    }
}

__global__ void k_output(const float2* __restrict__ b, float* __restrict__ out) {
    for (int e = blockIdx.x * blockDim.x + threadIdx.x; e < DHWn; e += gridDim.x * blockDim.x) {
        int d = e / HWn, rem = e - d * HWn;
        int h = rem / Wn, w = rem - h * Wn;
        int hs = h + Hn / 2; if (hs >= Hn) hs -= Hn;
        int ws = w + Wn / 2; if (ws >= Wn) ws -= Wn;
        float2 v = b[d * HWn + hs * Wn + ws];
        out[e] = v.x;
        out[DHWn + e] = v.y;
    }
}

extern "C" void kernel_launch(void* const* d_in, const int* in_sizes, int n_in,
                              void* d_out, int out_size, void* d_ws, size_t ws_size,
                              hipStream_t stream) {
    const float* z      = (const float*)d_in[0];
    const float* zf     = (const float*)d_in[1];
    const float* coil_r = (const float*)d_in[2];
    const float* coil_i = (const float*)d_in[3];
    const int*   maskp  = (const int*)d_in[4];
    const float* miu    = (const float*)d_in[5];
    float* out = (float*)d_out;

    char* w = (char*)d_ws;
    size_t off = 0;
    auto carve = [&](size_t bytes) -> void* {
        void* ptr = w + off;
        off += (bytes + 511) & ~(size_t)511;
        return ptr;
    };
    float2* P     = (float2*)carve((size_t)DHWn * 8);
    float2* R     = (float2*)carve((size_t)DHWn * 8);
    float2* Bv    = (float2*)carve((size_t)DHWn * 8);
    float2* Q     = (float2*)carve((size_t)DHWn * 8);
    float2* COIL  = (float2*)carve((size_t)Cn * HWn * 8);
    float*  MASKP = (float*)carve((size_t)HWn * 4);
    float2* TWS   = (float2*)carve(TW_N2 * 8);
    double* S     = (double*)carve(64 * 8);

    size_t imgSet = (size_t)DHWn * 8;   // one coil-slot (12 slices), 9.63 MB
    int cc = 1;
    {
        const int opts[4] = {10, 5, 2, 1};
        for (int i = 0; i < 4; ++i) {
            if (off + (size_t)opts[i] * imgSet <= ws_size) { cc = opts[i]; break; }
        }
    }
    float2* Y1T = (float2*)carve((size_t)cc * imgSet);   // staged lines [c][d][L][h]
    int nch = Cn / cc;

    k_init_misc<<<1, 256, 0, stream>>>(TWS, S);
    k_build_p<<<1024, 256, 0, stream>>>(z, zf, miu, P, R, Bv, S);
    k_build_coil<<<1024, 256, 0, stream>>>(coil_r, coil_i, COIL);
    k_build_mask<<<512, 256, 0, stream>>>(maskp, MASKP);

    for (int it = 0; it < 5; ++it) {
        for (int ch = 0; ch < nch; ++ch) {
            int cs = ch * cc;
            dim3 gf(Hn / 8, Dn, cc);   // 56 x 12 x cc
            dim3 gc(Wn / 4, Dn, cc);   // 56 x 12 x cc
            dim3 gi(Hn / 8, Dn);       // 56 x 12, loops over cc coils
            k_rowfft0<<<gf, 256, 0, stream>>>(P, COIL, Y1T, TWS, cs);
            k_colfft<<<gc, 256, 0, stream>>>(Y1T, MASKP, TWS);
            k_irow_combine<<<gi, 256, 0, stream>>>(Y1T, COIL, P, Q, miu, S, TWS,
                                                   cc, cs, ch == 0 ? 1 : 0,
                                                   ch == nch - 1 ? 1 : 0, it);
        }
        k_update_br<<<1024, 256, 0, stream>>>(S, S, it, (const float4*)P, (const float4*)Q,
                                              (float4*)Bv, (float4*)R);
        if (it < 4) k_update_p<<<1024, 256, 0, stream>>>(S, it, (const float4*)R, (float4*)P);
    }
    k_output<<<1024, 256, 0, stream>>>(Bv, out);
}